// Round 1
// baseline (404.643 us; speedup 1.0000x reference)
//
#include <hip/hip_runtime.h>
#include <hip/hip_bf16.h>

#define EPSV 1e-5f

__device__ __forceinline__ float softplus_f(float x){
    return fmaxf(x, 0.f) + log1pf(expf(-fabsf(x)));
}

// dinv[v] = rsqrt(deg[v]) per level; out-edges of pooled node v are e = v*(8<<S) + t
template<int S>
__global__ void k_dinv(const float* __restrict__ ew, const int* __restrict__ ei_src,
                       const int* __restrict__ ei_dst, float* __restrict__ dinv, int n){
    int v = blockIdx.x * blockDim.x + threadIdx.x;
    if (v >= n) return;
    const int EPN = 8 << S;
    float deg = 0.f;
    int base = v * EPN;
    #pragma unroll
    for (int t = 0; t < EPN; ++t){
        int e = base + t;
        float w = ew[e];
        int s_ = ei_src[e] >> S, d_ = ei_dst[e] >> S;
        if (s_ == d_) w = 0.f;   // never true at S=0 (offsets 1..8 mod 32)
        deg += w;
    }
    dinv[v] = (deg > 0.f) ? rsqrtf(deg) : 0.f;
}

template<int S>
__global__ void k_norm(const float* __restrict__ ew, const int* __restrict__ ei_src,
                       const int* __restrict__ ei_dst, const float* __restrict__ dinv,
                       float* __restrict__ norm, int E){
    int e = blockIdx.x * blockDim.x + threadIdx.x;
    if (e >= E) return;
    int s_ = ei_src[e] >> S, d_ = ei_dst[e] >> S;
    float w = (s_ == d_) ? 0.f : ew[e];
    norm[e] = -dinv[s_] * w * dinv[d_];
}

// tx[v,c] = sum over in-edges of node v (level S): norm[e] * xin[src_pooled, c]
template<int S, int C>
__global__ void k_gather(const float* __restrict__ norm, const int* __restrict__ ei_src,
                         const float* __restrict__ xin, float* __restrict__ tx, int n){
    int t = blockIdx.x * blockDim.x + threadIdx.x;
    if (t >= n * C) return;
    int v = t / C, c = t % C;
    int g = v >> (5 - S);
    int j = v & ((32 >> S) - 1);
    float acc = 0.f;
    #pragma unroll
    for (int m = 0; m < (1 << S); ++m){
        int d = (j << S) + m;            // original-resolution dst local id
        #pragma unroll
        for (int k = 0; k < 8; ++k){
            int sl = (d - k - 1) & 31;   // original src local
            int e  = g * 256 + sl * 8 + k;
            int u  = ei_src[e] >> S;     // pooled global src id
            acc += norm[e] * xin[u * C + c];
        }
    }
    tx[t] = acc;
}

// h[v,c] = sum_k xin[v,k]*Wa[k,c] + tx[v,k]*Wb[k,c] + bias[c]
template<int C_IN, int C_OUT>
__global__ __launch_bounds__(256) void k_gemm(const float* __restrict__ xin, const float* __restrict__ tx,
        const float* __restrict__ Wa, const float* __restrict__ Wb,
        const float* __restrict__ bias, float* __restrict__ h){
    __shared__ float xs[64][36];
    __shared__ float ts[64][36];
    __shared__ float wa[32][C_OUT];
    __shared__ float wb[32][C_OUT];
    int tid = threadIdx.x, blk = blockIdx.x;
    int row = tid >> 2, cg = tid & 3;
    constexpr int JN = C_OUT / 4;
    float acc[JN];
    #pragma unroll
    for (int j = 0; j < JN; ++j) acc[j] = 0.f;

    for (int kt = 0; kt < C_IN; kt += 32){
        __syncthreads();
        // stage x/tx k-tile: 64 rows x 32 cols = 512 float4
        for (int i4 = tid; i4 < 512; i4 += 256){
            int r = i4 >> 3, kk = i4 & 7;
            *reinterpret_cast<float4*>(&xs[r][kk*4]) =
                *(reinterpret_cast<const float4*>(xin + ((size_t)(blk*64 + r)*C_IN + kt)) + kk);
            *reinterpret_cast<float4*>(&ts[r][kk*4]) =
                *(reinterpret_cast<const float4*>(tx  + ((size_t)(blk*64 + r)*C_IN + kt)) + kk);
        }
        // stage W k-tile: 32 x C_OUT each
        for (int i4 = tid; i4 < 32*C_OUT/4; i4 += 256){
            int r = i4 / (C_OUT/4), cc = i4 % (C_OUT/4);
            *reinterpret_cast<float4*>(&wa[r][cc*4]) =
                *(reinterpret_cast<const float4*>(Wa + (size_t)(kt + r)*C_OUT) + cc);
            *reinterpret_cast<float4*>(&wb[r][cc*4]) =
                *(reinterpret_cast<const float4*>(Wb + (size_t)(kt + r)*C_OUT) + cc);
        }
        __syncthreads();
        #pragma unroll
        for (int kk = 0; kk < 32; ++kk){
            float a = xs[row][kk], t = ts[row][kk];
            #pragma unroll
            for (int j = 0; j < JN; ++j){
                int c = cg + j*4;
                acc[j] = fmaf(a, wa[kk][c], acc[j]);
                acc[j] = fmaf(t, wb[kk][c], acc[j]);
            }
        }
    }
    #pragma unroll
    for (int j = 0; j < JN; ++j){
        int c = cg + j*4;
        h[(size_t)(blk*64 + row)*C_OUT + c] = acc[j] + bias[c];
    }
}

template<int C>
__global__ void k_stats(const float* __restrict__ h, float* __restrict__ sums,
                        float* __restrict__ sumsq, size_t total){
    __shared__ float ls[C], lq[C];
    int tid = threadIdx.x;
    for (int i = tid; i < C; i += 256){ ls[i] = 0.f; lq[i] = 0.f; }
    __syncthreads();
    size_t T = (size_t)gridDim.x * 256;
    float s = 0.f, q = 0.f;
    for (size_t i = (size_t)blockIdx.x*256 + tid; i < total; i += T){
        float v = h[i]; s += v; q += v*v;
    }
    int c = tid & (C - 1);   // valid: 256 % C == 0 and T % C == 0
    atomicAdd(&ls[c], s);
    atomicAdd(&lq[c], q);
    __syncthreads();
    for (int i = tid; i < C; i += 256){
        atomicAdd(&sums[i],  ls[i]);
        atomicAdd(&sumsq[i], lq[i]);
    }
}

template<int C>
__global__ void k_bnsp_pool(const float* __restrict__ h, const float* __restrict__ sums,
        const float* __restrict__ sumsq, const float* __restrict__ gamma,
        const float* __restrict__ beta, float nl_inv, float* __restrict__ xout, size_t total_out){
    size_t t = (size_t)blockIdx.x * blockDim.x + threadIdx.x;
    if (t >= total_out) return;
    int c = (int)(t % C);
    size_t vo = t / C;
    float m = sums[c] * nl_inv;
    float var = sumsq[c] * nl_inv - m * m;
    float rstd = rsqrtf(var + EPSV);
    float ga = gamma[c], be = beta[c];
    float a  = h[(2*vo)*C + c];
    float b2 = h[(2*vo + 1)*C + c];
    a  = softplus_f((a  - m) * rstd * ga + be);
    b2 = softplus_f((b2 - m) * rstd * ga + be);
    xout[t] = fmaxf(a, b2);
}

__global__ void k_head(const float* __restrict__ h3, const float* __restrict__ sums,
        const float* __restrict__ sumsq, const float* __restrict__ gamma,
        const float* __restrict__ beta, const float* __restrict__ fcW,
        const float* __restrict__ fcb, float* __restrict__ out){
    __shared__ float4 part[128];
    int g = blockIdx.x, c = threadIdx.x;
    const float nl_inv = 1.f / 16384.f;
    float m = sums[c] * nl_inv;
    float var = sumsq[c] * nl_inv - m * m;
    float rstd = rsqrtf(var + EPSV);
    float ga = gamma[c], be = beta[c];
    float acc = 0.f;
    #pragma unroll
    for (int nn = 0; nn < 8; ++nn){
        float z = h3[(size_t)(g*8 + nn)*128 + c];
        acc += softplus_f((z - m) * rstd * ga + be);
    }
    float hg = acc * 0.125f;
    float4 w = *(reinterpret_cast<const float4*>(fcW) + c);
    part[c] = make_float4(hg*w.x, hg*w.y, hg*w.z, hg*w.w);
    __syncthreads();
    for (int s = 64; s > 0; s >>= 1){
        if (c < s){
            float4 o = part[c + s];
            part[c].x += o.x; part[c].y += o.y; part[c].z += o.z; part[c].w += o.w;
        }
        __syncthreads();
    }
    if (c == 0){
        float z0 = part[0].x + fcb[0], z1 = part[0].y + fcb[1];
        float z2 = part[0].z + fcb[2], z3 = part[0].w + fcb[3];
        float mx = fmaxf(fmaxf(z0, z1), fmaxf(z2, z3));
        float lse = mx + logf(expf(z0-mx) + expf(z1-mx) + expf(z2-mx) + expf(z3-mx));
        float* o = out + (size_t)g*4;
        o[0] = z0 - lse; o[1] = z1 - lse; o[2] = z2 - lse; o[3] = z3 - lse;
    }
}

extern "C" void kernel_launch(void* const* d_in, const int* in_sizes, int n_in,
                              void* d_out, int out_size, void* d_ws, size_t ws_size,
                              hipStream_t stream){
    const float* x   = (const float*)d_in[0];
    const float* ew  = (const float*)d_in[1];
    const float* W1a = (const float*)d_in[2];
    const float* W1b = (const float*)d_in[3];
    const float* b1  = (const float*)d_in[4];
    const float* g1  = (const float*)d_in[5];
    const float* be1 = (const float*)d_in[6];
    const float* W2a = (const float*)d_in[7];
    const float* W2b = (const float*)d_in[8];
    const float* b2  = (const float*)d_in[9];
    const float* g2  = (const float*)d_in[10];
    const float* be2 = (const float*)d_in[11];
    const float* W3a = (const float*)d_in[12];
    const float* W3b = (const float*)d_in[13];
    const float* b3  = (const float*)d_in[14];
    const float* g3  = (const float*)d_in[15];
    const float* be3 = (const float*)d_in[16];
    const float* fcW = (const float*)d_in[17];
    const float* fcb = (const float*)d_in[18];
    const int*   ei  = (const int*)d_in[19];
    float* out = (float*)d_out;

    const int E = 524288;
    const int* ei_src = ei;
    const int* ei_dst = ei + E;

    float* ws   = (float*)d_ws;
    float* dinv = ws;                    // 65536
    float* norm = dinv + 65536;          // 524288
    float* tx   = norm + 524288;         // 4194304 (max over levels)
    float* h    = tx   + 4194304;        // 4194304 (max over levels)
    float* xp   = h    + 4194304;        // 2097152 (x2: 32768 x 64)
    float* xp2  = xp   + 2097152;        // 2097152 (x3: 16384 x 128)
    float* st   = xp2  + 2097152;        // 640 floats of stats
    float* sum1 = st,       *sq1 = st + 64;
    float* sum2 = st + 192, *sq2 = st + 320;
    float* sum3 = st + 448, *sq3 = st + 576;

    hipMemsetAsync(st, 0, 640 * sizeof(float), stream);

    // ---- Level 1: N=65536, 64 -> 64
    k_dinv<0><<<65536/256, 256, 0, stream>>>(ew, ei_src, ei_dst, dinv, 65536);
    k_norm<0><<<E/256, 256, 0, stream>>>(ew, ei_src, ei_dst, dinv, norm, E);
    k_gather<0,64><<<(65536*64)/256, 256, 0, stream>>>(norm, ei_src, x, tx, 65536);
    k_gemm<64,64><<<65536/64, 256, 0, stream>>>(x, tx, W1a, W1b, b1, h);
    k_stats<64><<<256, 256, 0, stream>>>(h, sum1, sq1, (size_t)65536*64);
    k_bnsp_pool<64><<<(32768*64)/256, 256, 0, stream>>>(h, sum1, sq1, g1, be1,
                                                        1.f/65536.f, xp, (size_t)32768*64);
    // ---- Level 2: N=32768, 64 -> 128
    k_dinv<1><<<32768/256, 256, 0, stream>>>(ew, ei_src, ei_dst, dinv, 32768);
    k_norm<1><<<E/256, 256, 0, stream>>>(ew, ei_src, ei_dst, dinv, norm, E);
    k_gather<1,64><<<(32768*64)/256, 256, 0, stream>>>(norm, ei_src, xp, tx, 32768);
    k_gemm<64,128><<<32768/64, 256, 0, stream>>>(xp, tx, W2a, W2b, b2, h);
    k_stats<128><<<256, 256, 0, stream>>>(h, sum2, sq2, (size_t)32768*128);
    k_bnsp_pool<128><<<(16384*128)/256, 256, 0, stream>>>(h, sum2, sq2, g2, be2,
                                                          1.f/32768.f, xp2, (size_t)16384*128);
    // ---- Level 3: N=16384, 128 -> 128
    k_dinv<2><<<16384/256, 256, 0, stream>>>(ew, ei_src, ei_dst, dinv, 16384);
    k_norm<2><<<E/256, 256, 0, stream>>>(ew, ei_src, ei_dst, dinv, norm, E);
    k_gather<2,128><<<(16384*128)/256, 256, 0, stream>>>(norm, ei_src, xp2, tx, 16384);
    k_gemm<128,128><<<16384/64, 256, 0, stream>>>(xp2, tx, W3a, W3b, b3, h);
    k_stats<128><<<256, 256, 0, stream>>>(h, sum3, sq3, (size_t)16384*128);
    // ---- Head: BN3 + softplus + graph-mean + FC + log_softmax
    k_head<<<2048, 128, 0, stream>>>(h, sum3, sq3, g3, be3, fcW, fcb, out);
}

// Round 2
// 223.501 us; speedup vs baseline: 1.8105x; 1.8105x over previous
//
#include <hip/hip_runtime.h>

#define EPSV 1e-5f

typedef __attribute__((ext_vector_type(8))) short short8;
typedef __attribute__((ext_vector_type(4))) float f32x4;

__device__ __forceinline__ float softplus_f(float x){
    return fmaxf(x, 0.f) + log1pf(expf(-fabsf(x)));
}
__device__ __forceinline__ float bf2f(short u){
    union{unsigned int i; float f;} x; x.i = ((unsigned int)(unsigned short)u) << 16; return x.f;
}
__device__ __forceinline__ short f2bf(float f){
    union{float f; unsigned int i;} x; x.f = f;
    unsigned int r = x.i + 0x7fffu + ((x.i >> 16) & 1u);
    return (short)(r >> 16);
}

// ---- W pre-transpose + bf16 convert: wt[c*SP + k] = bf16(W[k*N + c])
#define W1TA_OFF 0
#define W1TB_OFF 4608
#define W2TA_OFF 9216
#define W2TB_OFF 18432
#define W3TA_OFF 27648
#define W3TB_OFF 45056
#define WT_TOTAL 62464

__global__ void k_prep(const float* __restrict__ W1a, const float* __restrict__ W1b,
                       const float* __restrict__ W2a, const float* __restrict__ W2b,
                       const float* __restrict__ W3a, const float* __restrict__ W3b,
                       short* __restrict__ wt){
    int blk = blockIdx.x, tid = threadIdx.x;
    const float* src; short* dst; int N, SP, base;
    if      (blk < 16){  src = W1a; dst = wt + W1TA_OFF; N = 64;  SP = 72;  base = blk; }
    else if (blk < 32){  src = W1b; dst = wt + W1TB_OFF; N = 64;  SP = 72;  base = blk - 16; }
    else if (blk < 64){  src = W2a; dst = wt + W2TA_OFF; N = 128; SP = 72;  base = blk - 32; }
    else if (blk < 96){  src = W2b; dst = wt + W2TB_OFF; N = 128; SP = 72;  base = blk - 64; }
    else if (blk < 160){ src = W3a; dst = wt + W3TA_OFF; N = 128; SP = 136; base = blk - 96; }
    else              {  src = W3b; dst = wt + W3TB_OFF; N = 128; SP = 136; base = blk - 160; }
    int e = base * 256 + tid;
    int k = e / N, c = e % N;
    dst[c * SP + k] = f2bf(src[e]);
}

// ---- Level 1 fused: deg/norm/gather/GEMM(32x64,K=64) per graph
__global__ __launch_bounds__(256) void k_conv1(const float* __restrict__ x, const float* __restrict__ ew,
        const short* __restrict__ w1ta, const short* __restrict__ w1tb,
        const float* __restrict__ b1, short* __restrict__ h1){
    __shared__ float ews[256], nrm[256], dinv[32];
    __shared__ __align__(16) short xsb[32][72];
    __shared__ __align__(16) short tsb[32][72];
    __shared__ __align__(16) short wla[64][72];
    __shared__ __align__(16) short wlb[64][72];
    int g = blockIdx.x, tid = threadIdx.x;
    ews[tid] = ew[(size_t)g*256 + tid];
    {   // stage x -> bf16 LDS: 32x64 fp32 = 512 float4
        const float4* xg = (const float4*)(x + (size_t)g*32*64);
        #pragma unroll
        for (int p = 0; p < 2; ++p){
            int i4 = tid + p*256;
            int r = i4 >> 4, cc = (i4 & 15)*4;
            float4 v = xg[i4];
            xsb[r][cc+0] = f2bf(v.x); xsb[r][cc+1] = f2bf(v.y);
            xsb[r][cc+2] = f2bf(v.z); xsb[r][cc+3] = f2bf(v.w);
        }
    }
    {   // stage W1 (bf16, [col][k] stride 72)
        int c = tid >> 2, k0 = (tid & 3)*16;
        *(short8*)&wla[c][k0]   = *(const short8*)&w1ta[c*72 + k0];
        *(short8*)&wla[c][k0+8] = *(const short8*)&w1ta[c*72 + k0 + 8];
        *(short8*)&wlb[c][k0]   = *(const short8*)&w1tb[c*72 + k0];
        *(short8*)&wlb[c][k0+8] = *(const short8*)&w1tb[c*72 + k0 + 8];
    }
    __syncthreads();
    if (tid < 32){
        float d = 0.f;
        #pragma unroll
        for (int k = 0; k < 8; ++k) d += ews[tid*8 + k];
        dinv[tid] = d > 0.f ? rsqrtf(d) : 0.f;
    }
    __syncthreads();
    {   int se = tid >> 3, de = (se + (tid & 7) + 1) & 31;
        nrm[tid] = -dinv[se] * ews[tid] * dinv[de]; }
    __syncthreads();
    {   // gather: tx[v][ch..ch+7]
        int v = tid >> 3, ch = (tid & 7)*8;
        float acc[8];
        #pragma unroll
        for (int j = 0; j < 8; ++j) acc[j] = 0.f;
        #pragma unroll
        for (int k = 0; k < 8; ++k){
            int sl = (v - k - 1) & 31;
            float nw = nrm[sl*8 + k];
            short8 xv = *(const short8*)&xsb[sl][ch];
            #pragma unroll
            for (int j = 0; j < 8; ++j) acc[j] = fmaf(nw, bf2f(xv[j]), acc[j]);
        }
        short8 o;
        #pragma unroll
        for (int j = 0; j < 8; ++j) o[j] = f2bf(acc[j]);
        *(short8*)&tsb[v][ch] = o;
    }
    __syncthreads();
    // MFMA GEMM: wave w: rows rt*16, cols cp*32 (2 col-tiles)
    int lane = tid & 63, w = tid >> 6;
    int lrow = lane & 15, lk8 = lane >> 4;
    int rt = w & 1, cp = w >> 1;
    f32x4 acc0 = {0,0,0,0}, acc1 = {0,0,0,0};
    #pragma unroll
    for (int ks = 0; ks < 2; ++ks){
        int kb = ks*32 + lk8*8;
        short8 ax  = *(const short8*)&xsb[rt*16 + lrow][kb];
        short8 at  = *(const short8*)&tsb[rt*16 + lrow][kb];
        short8 b0a = *(const short8*)&wla[cp*32 + lrow][kb];
        short8 b0b = *(const short8*)&wlb[cp*32 + lrow][kb];
        short8 b1a = *(const short8*)&wla[cp*32 + 16 + lrow][kb];
        short8 b1b = *(const short8*)&wlb[cp*32 + 16 + lrow][kb];
        acc0 = __builtin_amdgcn_mfma_f32_16x16x32_bf16(ax, b0a, acc0, 0, 0, 0);
        acc0 = __builtin_amdgcn_mfma_f32_16x16x32_bf16(at, b0b, acc0, 0, 0, 0);
        acc1 = __builtin_amdgcn_mfma_f32_16x16x32_bf16(ax, b1a, acc1, 0, 0, 0);
        acc1 = __builtin_amdgcn_mfma_f32_16x16x32_bf16(at, b1b, acc1, 0, 0, 0);
    }
    {   int c0 = cp*32 + lrow, c1 = c0 + 16;
        float bb0 = b1[c0], bb1 = b1[c1];
        size_t rowbase = (size_t)g*32 + rt*16 + lk8*4;
        #pragma unroll
        for (int e2 = 0; e2 < 4; ++e2){
            h1[(rowbase + e2)*64 + c0] = f2bf(acc0[e2] + bb0);
            h1[(rowbase + e2)*64 + c1] = f2bf(acc1[e2] + bb1);
        }
    }
}

// ---- Level 2 fused: BN1+softplus+pool, deg/norm/gather, GEMM(16x128,K=64)
__global__ __launch_bounds__(256) void k_conv2(const short* __restrict__ h1, const float* __restrict__ ew,
        const float* __restrict__ sum1, const float* __restrict__ sq1,
        const float* __restrict__ g1, const float* __restrict__ be1,
        const short* __restrict__ w2ta, const short* __restrict__ w2tb,
        const float* __restrict__ b2, short* __restrict__ h2){
    __shared__ float ews[256], nrm[256], dinv[16];
    __shared__ float scl[64], sft[64];
    __shared__ __align__(16) short xpb[16][72];
    __shared__ __align__(16) short tsb[16][72];
    __shared__ __align__(16) short wla[128][72];
    __shared__ __align__(16) short wlb[128][72];
    int g = blockIdx.x, tid = threadIdx.x;
    ews[tid] = ew[(size_t)g*256 + tid];
    if (tid < 64){
        float m = sum1[tid] * (1.f/65536.f);
        float v = sq1[tid] * (1.f/65536.f) - m*m;
        float rs = rsqrtf(v + EPSV) * g1[tid];
        scl[tid] = rs; sft[tid] = be1[tid] - m*rs;
    }
    {   int c = tid >> 1, k0 = (tid & 1)*32;
        #pragma unroll
        for (int p = 0; p < 4; ++p){
            *(short8*)&wla[c][k0 + p*8] = *(const short8*)&w2ta[c*72 + k0 + p*8];
            *(short8*)&wlb[c][k0 + p*8] = *(const short8*)&w2tb[c*72 + k0 + p*8];
        }
    }
    __syncthreads();
    if (tid < 128){   // BN1 + softplus + pool-max -> xpb
        int vo = tid >> 3, ch = (tid & 7)*8;
        short8 a = *(const short8*)&h1[((size_t)g*32 + 2*vo)*64 + ch];
        short8 b = *(const short8*)&h1[((size_t)g*32 + 2*vo + 1)*64 + ch];
        short8 o;
        #pragma unroll
        for (int j = 0; j < 8; ++j){
            float s = scl[ch+j], t = sft[ch+j];
            float va = softplus_f(bf2f(a[j])*s + t);
            float vb = softplus_f(bf2f(b[j])*s + t);
            o[j] = f2bf(fmaxf(va, vb));
        }
        *(short8*)&xpb[vo][ch] = o;
    }
    if (tid < 16){
        float d = 0.f;
        for (int t = tid*16; t < tid*16 + 16; ++t){
            int se = t >> 3, de = (se + (t & 7) + 1) & 31;
            float wv = ((se >> 1) == (de >> 1)) ? 0.f : ews[t];
            d += wv;
        }
        dinv[tid] = d > 0.f ? rsqrtf(d) : 0.f;
    }
    __syncthreads();
    {   int se = tid >> 3, de = (se + (tid & 7) + 1) & 31;
        float wv = ((se >> 1) == (de >> 1)) ? 0.f : ews[tid];
        nrm[tid] = -dinv[se >> 1] * wv * dinv[de >> 1]; }
    __syncthreads();
    if (tid < 128){   // gather over 16 in-edges
        int v = tid >> 3, ch = (tid & 7)*8;
        float acc[8];
        #pragma unroll
        for (int j = 0; j < 8; ++j) acc[j] = 0.f;
        #pragma unroll
        for (int dd = 0; dd < 2; ++dd){
            int d = v*2 + dd;
            #pragma unroll
            for (int k = 0; k < 8; ++k){
                int sl = (d - k - 1) & 31;
                float nw = nrm[sl*8 + k];
                short8 xv = *(const short8*)&xpb[sl >> 1][ch];
                #pragma unroll
                for (int j = 0; j < 8; ++j) acc[j] = fmaf(nw, bf2f(xv[j]), acc[j]);
            }
        }
        short8 o;
        #pragma unroll
        for (int j = 0; j < 8; ++j) o[j] = f2bf(acc[j]);
        *(short8*)&tsb[v][ch] = o;
    }
    __syncthreads();
    int lane = tid & 63, w = tid >> 6, lrow = lane & 15, lk8 = lane >> 4;
    f32x4 acc0 = {0,0,0,0}, acc1 = {0,0,0,0};
    #pragma unroll
    for (int ks = 0; ks < 2; ++ks){
        int kb = ks*32 + lk8*8;
        short8 ax  = *(const short8*)&xpb[lrow][kb];
        short8 at  = *(const short8*)&tsb[lrow][kb];
        short8 b0a = *(const short8*)&wla[w*32 + lrow][kb];
        short8 b0b = *(const short8*)&wlb[w*32 + lrow][kb];
        short8 b1a = *(const short8*)&wla[w*32 + 16 + lrow][kb];
        short8 b1b = *(const short8*)&wlb[w*32 + 16 + lrow][kb];
        acc0 = __builtin_amdgcn_mfma_f32_16x16x32_bf16(ax, b0a, acc0, 0, 0, 0);
        acc0 = __builtin_amdgcn_mfma_f32_16x16x32_bf16(at, b0b, acc0, 0, 0, 0);
        acc1 = __builtin_amdgcn_mfma_f32_16x16x32_bf16(ax, b1a, acc1, 0, 0, 0);
        acc1 = __builtin_amdgcn_mfma_f32_16x16x32_bf16(at, b1b, acc1, 0, 0, 0);
    }
    {   int c0 = w*32 + lrow, c1 = c0 + 16;
        float bb0 = b2[c0], bb1 = b2[c1];
        size_t rowbase = (size_t)g*16 + lk8*4;
        #pragma unroll
        for (int e2 = 0; e2 < 4; ++e2){
            h2[(rowbase + e2)*128 + c0] = f2bf(acc0[e2] + bb0);
            h2[(rowbase + e2)*128 + c1] = f2bf(acc1[e2] + bb1);
        }
    }
}

// ---- Level 3 fused: BN2+softplus+pool, deg/norm/gather, GEMM(8x128,K=128, 2 col-chunks)
__global__ __launch_bounds__(256) void k_conv3(const short* __restrict__ h2, const float* __restrict__ ew,
        const float* __restrict__ sum2, const float* __restrict__ sq2,
        const float* __restrict__ g2, const float* __restrict__ be2,
        const short* __restrict__ w3ta, const short* __restrict__ w3tb,
        const float* __restrict__ b3, short* __restrict__ h3){
    __shared__ float ews[256], nrm[256], dinv[8];
    __shared__ float scl[128], sft[128];
    __shared__ __align__(16) short xpb[16][136];
    __shared__ __align__(16) short tsb[16][136];
    __shared__ __align__(16) short wca[64][136];
    __shared__ __align__(16) short wcb[64][136];
    int g = blockIdx.x, tid = threadIdx.x;
    ews[tid] = ew[(size_t)g*256 + tid];
    if (tid < 128){
        float m = sum2[tid] * (1.f/32768.f);
        float v = sq2[tid] * (1.f/32768.f) - m*m;
        float rs = rsqrtf(v + EPSV) * g2[tid];
        scl[tid] = rs; sft[tid] = be2[tid] - m*rs;
    }
    for (int idx = tid; idx < 8*136; idx += 256){   // zero pad rows 8..15
        int r = 8 + idx/136, c = idx % 136;
        xpb[r][c] = 0; tsb[r][c] = 0;
    }
    __syncthreads();
    if (tid < 128){   // BN2 + softplus + pool-max
        int vo = tid >> 4, ch = (tid & 15)*8;
        short8 a = *(const short8*)&h2[((size_t)g*16 + 2*vo)*128 + ch];
        short8 b = *(const short8*)&h2[((size_t)g*16 + 2*vo + 1)*128 + ch];
        short8 o;
        #pragma unroll
        for (int j = 0; j < 8; ++j){
            float s = scl[ch+j], t = sft[ch+j];
            float va = softplus_f(bf2f(a[j])*s + t);
            float vb = softplus_f(bf2f(b[j])*s + t);
            o[j] = f2bf(fmaxf(va, vb));
        }
        *(short8*)&xpb[vo][ch] = o;
    }
    if (tid < 8){
        float d = 0.f;
        for (int t = tid*32; t < tid*32 + 32; ++t){
            int se = t >> 3, de = (se + (t & 7) + 1) & 31;
            float wv = ((se >> 2) == (de >> 2)) ? 0.f : ews[t];
            d += wv;
        }
        dinv[tid] = d > 0.f ? rsqrtf(d) : 0.f;
    }
    __syncthreads();
    {   int se = tid >> 3, de = (se + (tid & 7) + 1) & 31;
        float wv = ((se >> 2) == (de >> 2)) ? 0.f : ews[tid];
        nrm[tid] = -dinv[se >> 2] * wv * dinv[de >> 2]; }
    __syncthreads();
    if (tid < 128){   // gather over 32 in-edges
        int v = tid >> 4, ch = (tid & 15)*8;
        float acc[8];
        #pragma unroll
        for (int j = 0; j < 8; ++j) acc[j] = 0.f;
        #pragma unroll
        for (int dd = 0; dd < 4; ++dd){
            int d = v*4 + dd;
            #pragma unroll
            for (int k = 0; k < 8; ++k){
                int sl = (d - k - 1) & 31;
                float nw = nrm[sl*8 + k];
                short8 xv = *(const short8*)&xpb[sl >> 2][ch];
                #pragma unroll
                for (int j = 0; j < 8; ++j) acc[j] = fmaf(nw, bf2f(xv[j]), acc[j]);
            }
        }
        short8 o;
        #pragma unroll
        for (int j = 0; j < 8; ++j) o[j] = f2bf(acc[j]);
        *(short8*)&tsb[v][ch] = o;
    }
    __syncthreads();
    int lane = tid & 63, w = tid >> 6, lrow = lane & 15, lk8 = lane >> 4;
    short8 ax[4], at[4];
    #pragma unroll
    for (int ks = 0; ks < 4; ++ks){
        int kb = ks*32 + lk8*8;
        ax[ks] = *(const short8*)&xpb[lrow][kb];
        at[ks] = *(const short8*)&tsb[lrow][kb];
    }
    #pragma unroll
    for (int cc = 0; cc < 2; ++cc){
        {   int c = tid >> 2, k0 = (tid & 3)*32;
            const short* pa = w3ta + ((size_t)(cc*64 + c))*136 + k0;
            const short* pb = w3tb + ((size_t)(cc*64 + c))*136 + k0;
            #pragma unroll
            for (int p = 0; p < 4; ++p){
                *(short8*)&wca[c][k0 + p*8] = *(const short8*)(pa + p*8);
                *(short8*)&wcb[c][k0 + p*8] = *(const short8*)(pb + p*8);
            }
        }
        __syncthreads();
        f32x4 acc = {0,0,0,0};
        #pragma unroll
        for (int ks = 0; ks < 4; ++ks){
            int kb = ks*32 + lk8*8;
            short8 ba = *(const short8*)&wca[w*16 + lrow][kb];
            short8 bb = *(const short8*)&wcb[w*16 + lrow][kb];
            acc = __builtin_amdgcn_mfma_f32_16x16x32_bf16(ax[ks], ba, acc, 0, 0, 0);
            acc = __builtin_amdgcn_mfma_f32_16x16x32_bf16(at[ks], bb, acc, 0, 0, 0);
        }
        if (lk8 < 2){
            int col = cc*64 + w*16 + lrow;
            float bb0 = b3[col];
            #pragma unroll
            for (int e2 = 0; e2 < 4; ++e2){
                int row = lk8*4 + e2;
                h3[((size_t)g*8 + row)*128 + col] = f2bf(acc[e2] + bb0);
            }
        }
        __syncthreads();
    }
}

// ---- per-channel sum/sumsq over bf16 h
template<int C>
__global__ void k_stats_bf(const short* __restrict__ h, float* __restrict__ sums,
                           float* __restrict__ sumsq, int total8){
    __shared__ float ls[C], lq[C];
    int tid = threadIdx.x;
    for (int i = tid; i < C; i += 256){ ls[i] = 0.f; lq[i] = 0.f; }
    __syncthreads();
    int T = gridDim.x * 256;
    float s[8], q[8];
    #pragma unroll
    for (int j = 0; j < 8; ++j){ s[j] = 0.f; q[j] = 0.f; }
    int i0 = blockIdx.x*256 + tid;
    for (int i = i0; i < total8; i += T){
        short8 v = *(const short8*)&h[(size_t)i*8];
        #pragma unroll
        for (int j = 0; j < 8; ++j){ float f = bf2f(v[j]); s[j] += f; q[j] += f*f; }
    }
    int cb = (i0*8) % C;   // constant per thread: (T*8) % C == 0
    #pragma unroll
    for (int j = 0; j < 8; ++j){ atomicAdd(&ls[cb+j], s[j]); atomicAdd(&lq[cb+j], q[j]); }
    __syncthreads();
    for (int i = tid; i < C; i += 256){
        atomicAdd(&sums[i],  ls[i]);
        atomicAdd(&sumsq[i], lq[i]);
    }
}

// ---- head: BN3 + softplus + graph-mean + FC + log_softmax
__global__ void k_head_bf(const short* __restrict__ h3, const float* __restrict__ sums,
        const float* __restrict__ sumsq, const float* __restrict__ gamma,
        const float* __restrict__ beta, const float* __restrict__ fcW,
        const float* __restrict__ fcb, float* __restrict__ out){
    __shared__ float4 part[128];
    int g = blockIdx.x, c = threadIdx.x;
    const float nl_inv = 1.f/16384.f;
    float m = sums[c] * nl_inv;
    float var = sumsq[c] * nl_inv - m*m;
    float rstd = rsqrtf(var + EPSV);
    float ga = gamma[c], be = beta[c];
    float acc = 0.f;
    #pragma unroll
    for (int nn = 0; nn < 8; ++nn){
        float z = bf2f(h3[((size_t)g*8 + nn)*128 + c]);
        acc += softplus_f((z - m)*rstd*ga + be);
    }
    float hg = acc * 0.125f;
    float4 w = *(reinterpret_cast<const float4*>(fcW) + c);
    part[c] = make_float4(hg*w.x, hg*w.y, hg*w.z, hg*w.w);
    __syncthreads();
    for (int s = 64; s > 0; s >>= 1){
        if (c < s){
            float4 o = part[c + s];
            part[c].x += o.x; part[c].y += o.y; part[c].z += o.z; part[c].w += o.w;
        }
        __syncthreads();
    }
    if (c == 0){
        float z0 = part[0].x + fcb[0], z1 = part[0].y + fcb[1];
        float z2 = part[0].z + fcb[2], z3 = part[0].w + fcb[3];
        float mx = fmaxf(fmaxf(z0, z1), fmaxf(z2, z3));
        float lse = mx + logf(expf(z0-mx) + expf(z1-mx) + expf(z2-mx) + expf(z3-mx));
        float* o = out + (size_t)g*4;
        o[0] = z0 - lse; o[1] = z1 - lse; o[2] = z2 - lse; o[3] = z3 - lse;
    }
}

extern "C" void kernel_launch(void* const* d_in, const int* in_sizes, int n_in,
                              void* d_out, int out_size, void* d_ws, size_t ws_size,
                              hipStream_t stream){
    const float* x   = (const float*)d_in[0];
    const float* ew  = (const float*)d_in[1];
    const float* W1a = (const float*)d_in[2];
    const float* W1b = (const float*)d_in[3];
    const float* b1  = (const float*)d_in[4];
    const float* g1  = (const float*)d_in[5];
    const float* be1 = (const float*)d_in[6];
    const float* W2a = (const float*)d_in[7];
    const float* W2b = (const float*)d_in[8];
    const float* b2  = (const float*)d_in[9];
    const float* g2  = (const float*)d_in[10];
    const float* be2 = (const float*)d_in[11];
    const float* W3a = (const float*)d_in[12];
    const float* W3b = (const float*)d_in[13];
    const float* b3  = (const float*)d_in[14];
    const float* g3  = (const float*)d_in[15];
    const float* be3 = (const float*)d_in[16];
    const float* fcW = (const float*)d_in[17];
    const float* fcb = (const float*)d_in[18];
    float* out = (float*)d_out;
    (void)in_sizes; (void)n_in; (void)out_size; (void)ws_size;

    short* h1 = (short*)d_ws;                    // 65536*64  bf16
    short* h2 = h1 + (size_t)4194304;            // 32768*128 bf16
    short* h3 = h2 + (size_t)4194304;            // 16384*128 bf16
    short* wT = h3 + (size_t)2097152;            // 62464 shorts
    float* st = (float*)(((uintptr_t)(wT + WT_TOTAL) + 255) & ~(uintptr_t)255);
    float* sum1 = st,        *sq1 = st + 64;
    float* sum2 = st + 128,  *sq2 = st + 256;
    float* sum3 = st + 384,  *sq3 = st + 512;

    hipMemsetAsync(st, 0, 640*sizeof(float), stream);
    k_prep<<<224, 256, 0, stream>>>(W1a, W1b, W2a, W2b, W3a, W3b, wT);

    k_conv1<<<2048, 256, 0, stream>>>(x, ew, wT + W1TA_OFF, wT + W1TB_OFF, b1, h1);
    k_stats_bf<64><<<256, 256, 0, stream>>>(h1, sum1, sq1, 524288);

    k_conv2<<<2048, 256, 0, stream>>>(h1, ew, sum1, sq1, g1, be1,
                                      wT + W2TA_OFF, wT + W2TB_OFF, b2, h2);
    k_stats_bf<128><<<256, 256, 0, stream>>>(h2, sum2, sq2, 524288);

    k_conv3<<<2048, 256, 0, stream>>>(h2, ew, sum2, sq2, g2, be2,
                                      wT + W3TA_OFF, wT + W3TB_OFF, b3, h3);
    k_stats_bf<128><<<256, 256, 0, stream>>>(h3, sum3, sq3, 262144);

    k_head_bf<<<2048, 128, 0, stream>>>(h3, sum3, sq3, g3, be3, fcW, fcb, out);
}

// Round 4
// 214.735 us; speedup vs baseline: 1.8844x; 1.0408x over previous
//
#include <hip/hip_runtime.h>

#define EPSV 1e-5f

typedef __attribute__((ext_vector_type(8))) short short8;
typedef __attribute__((ext_vector_type(4))) float f32x4;

__device__ __forceinline__ float softplus_f(float x){
    return fmaxf(x, 0.f) + log1pf(expf(-fabsf(x)));
}
__device__ __forceinline__ float bf2f(short u){
    union{unsigned int i; float f;} x; x.i = ((unsigned int)(unsigned short)u) << 16; return x.f;
}
__device__ __forceinline__ short f2bf(float f){
    union{float f; unsigned int i;} x; x.f = f;
    unsigned int r = x.i + 0x7fffu + ((x.i >> 16) & 1u);
    return (short)(r >> 16);
}

// ---- W pre-transpose + bf16 convert: wt[c*SP + k] = bf16(W[k*N + c])
#define W1TA_OFF 0
#define W1TB_OFF 4608
#define W2TA_OFF 9216
#define W2TB_OFF 18432
#define W3TA_OFF 27648
#define W3TB_OFF 45056
#define WT_TOTAL 62464

__global__ void k_prep(const float* __restrict__ W1a, const float* __restrict__ W1b,
                       const float* __restrict__ W2a, const float* __restrict__ W2b,
                       const float* __restrict__ W3a, const float* __restrict__ W3b,
                       short* __restrict__ wt){
    int blk = blockIdx.x, tid = threadIdx.x;
    const float* src; short* dst; int N, SP, base;
    if      (blk < 16){  src = W1a; dst = wt + W1TA_OFF; N = 64;  SP = 72;  base = blk; }
    else if (blk < 32){  src = W1b; dst = wt + W1TB_OFF; N = 64;  SP = 72;  base = blk - 16; }
    else if (blk < 64){  src = W2a; dst = wt + W2TA_OFF; N = 128; SP = 72;  base = blk - 32; }
    else if (blk < 96){  src = W2b; dst = wt + W2TB_OFF; N = 128; SP = 72;  base = blk - 64; }
    else if (blk < 160){ src = W3a; dst = wt + W3TA_OFF; N = 128; SP = 136; base = blk - 96; }
    else              {  src = W3b; dst = wt + W3TB_OFF; N = 128; SP = 136; base = blk - 160; }
    int e = base * 256 + tid;
    int k = e / N, c = e % N;
    dst[c * SP + k] = f2bf(src[e]);
}

// ---- Level 1 graph-local: x->bf16, deg/norm, gather  -> xb1, tx1
__global__ __launch_bounds__(256) void k_gat1(const float* __restrict__ x, const float* __restrict__ ew,
        short* __restrict__ xb1, short* __restrict__ tx1){
    __shared__ float ews[256], nrm[256], dinv[32];
    __shared__ __align__(16) short xsb[32][72];
    int g = blockIdx.x, tid = threadIdx.x;
    ews[tid] = ew[(size_t)g*256 + tid];
    {   const float4* xg = (const float4*)(x + (size_t)g*32*64);
        #pragma unroll
        for (int p = 0; p < 2; ++p){
            int i4 = tid + p*256;
            int r = i4 >> 4, cc = (i4 & 15)*4;
            float4 v = xg[i4];
            xsb[r][cc+0] = f2bf(v.x); xsb[r][cc+1] = f2bf(v.y);
            xsb[r][cc+2] = f2bf(v.z); xsb[r][cc+3] = f2bf(v.w);
        }
    }
    __syncthreads();
    if (tid < 32){
        float d = 0.f;
        #pragma unroll
        for (int k = 0; k < 8; ++k) d += ews[tid*8 + k];
        dinv[tid] = d > 0.f ? rsqrtf(d) : 0.f;
    }
    __syncthreads();
    {   int se = tid >> 3, de = (se + (tid & 7) + 1) & 31;
        nrm[tid] = -dinv[se] * ews[tid] * dinv[de]; }
    __syncthreads();
    int v = tid >> 3, ch = (tid & 7)*8;
    // write bf16 x
    *(short8*)&xb1[((size_t)g*32 + v)*64 + ch] = *(const short8*)&xsb[v][ch];
    // gather
    float acc[8];
    #pragma unroll
    for (int j = 0; j < 8; ++j) acc[j] = 0.f;
    #pragma unroll
    for (int k = 0; k < 8; ++k){
        int sl = (v - k - 1) & 31;
        float nw = nrm[sl*8 + k];
        short8 xv = *(const short8*)&xsb[sl][ch];
        #pragma unroll
        for (int j = 0; j < 8; ++j) acc[j] = fmaf(nw, bf2f(xv[j]), acc[j]);
    }
    short8 o;
    #pragma unroll
    for (int j = 0; j < 8; ++j) o[j] = f2bf(acc[j]);
    *(short8*)&tx1[((size_t)g*32 + v)*64 + ch] = o;
}

// ---- Level 2 graph-local: BN1+sp+pool, deg/norm, gather -> xb2, tx2
__global__ __launch_bounds__(256) void k_gat2(const short* __restrict__ h1, const float* __restrict__ ew,
        const float* __restrict__ scl1, const float* __restrict__ sft1,
        short* __restrict__ xb2, short* __restrict__ tx2){
    __shared__ float ews[256], nrm[256], dinv[16];
    __shared__ float scl[64], sft[64];
    __shared__ __align__(16) short xpb[16][72];
    int g = blockIdx.x, tid = threadIdx.x;
    ews[tid] = ew[(size_t)g*256 + tid];
    if (tid < 64){ scl[tid] = scl1[tid]; sft[tid] = sft1[tid]; }
    __syncthreads();
    if (tid < 128){   // BN1 + softplus + pool-max -> xpb + xb2
        int vo = tid >> 3, ch = (tid & 7)*8;
        short8 a = *(const short8*)&h1[((size_t)g*32 + 2*vo)*64 + ch];
        short8 b = *(const short8*)&h1[((size_t)g*32 + 2*vo + 1)*64 + ch];
        short8 o;
        #pragma unroll
        for (int j = 0; j < 8; ++j){
            float s = scl[ch+j], t = sft[ch+j];
            float va = softplus_f(bf2f(a[j])*s + t);
            float vb = softplus_f(bf2f(b[j])*s + t);
            o[j] = f2bf(fmaxf(va, vb));
        }
        *(short8*)&xpb[vo][ch] = o;
        *(short8*)&xb2[((size_t)g*16 + vo)*64 + ch] = o;
    }
    if (tid < 16){
        float d = 0.f;
        for (int t = tid*16; t < tid*16 + 16; ++t){
            int se = t >> 3, de = (se + (t & 7) + 1) & 31;
            float wv = ((se >> 1) == (de >> 1)) ? 0.f : ews[t];
            d += wv;
        }
        dinv[tid] = d > 0.f ? rsqrtf(d) : 0.f;
    }
    __syncthreads();
    {   int se = tid >> 3, de = (se + (tid & 7) + 1) & 31;
        float wv = ((se >> 1) == (de >> 1)) ? 0.f : ews[tid];
        nrm[tid] = -dinv[se >> 1] * wv * dinv[de >> 1]; }
    __syncthreads();
    if (tid < 128){
        int v = tid >> 3, ch = (tid & 7)*8;
        float acc[8];
        #pragma unroll
        for (int j = 0; j < 8; ++j) acc[j] = 0.f;
        #pragma unroll
        for (int dd = 0; dd < 2; ++dd){
            int d = v*2 + dd;
            #pragma unroll
            for (int k = 0; k < 8; ++k){
                int sl = (d - k - 1) & 31;
                float nw = nrm[sl*8 + k];
                short8 xv = *(const short8*)&xpb[sl >> 1][ch];
                #pragma unroll
                for (int j = 0; j < 8; ++j) acc[j] = fmaf(nw, bf2f(xv[j]), acc[j]);
            }
        }
        short8 o;
        #pragma unroll
        for (int j = 0; j < 8; ++j) o[j] = f2bf(acc[j]);
        *(short8*)&tx2[((size_t)g*16 + v)*64 + ch] = o;
    }
}

// ---- Level 3 graph-local: BN2+sp+pool, deg/norm, gather -> xb3, tx3
__global__ __launch_bounds__(256) void k_gat3(const short* __restrict__ h2, const float* __restrict__ ew,
        const float* __restrict__ scl2, const float* __restrict__ sft2,
        short* __restrict__ xb3, short* __restrict__ tx3){
    __shared__ float ews[256], nrm[256], dinv[8];
    __shared__ float scl[128], sft[128];
    __shared__ __align__(16) short xpb[8][136];
    int g = blockIdx.x, tid = threadIdx.x;
    ews[tid] = ew[(size_t)g*256 + tid];
    if (tid < 128){ scl[tid] = scl2[tid]; sft[tid] = sft2[tid]; }
    __syncthreads();
    if (tid < 128){   // BN2 + softplus + pool-max
        int vo = tid >> 4, ch = (tid & 15)*8;
        short8 a = *(const short8*)&h2[((size_t)g*16 + 2*vo)*128 + ch];
        short8 b = *(const short8*)&h2[((size_t)g*16 + 2*vo + 1)*128 + ch];
        short8 o;
        #pragma unroll
        for (int j = 0; j < 8; ++j){
            float s = scl[ch+j], t = sft[ch+j];
            float va = softplus_f(bf2f(a[j])*s + t);
            float vb = softplus_f(bf2f(b[j])*s + t);
            o[j] = f2bf(fmaxf(va, vb));
        }
        *(short8*)&xpb[vo][ch] = o;
        *(short8*)&xb3[((size_t)g*8 + vo)*128 + ch] = o;
    }
    if (tid < 8){
        float d = 0.f;
        for (int t = tid*32; t < tid*32 + 32; ++t){
            int se = t >> 3, de = (se + (t & 7) + 1) & 31;
            float wv = ((se >> 2) == (de >> 2)) ? 0.f : ews[t];
            d += wv;
        }
        dinv[tid] = d > 0.f ? rsqrtf(d) : 0.f;
    }
    __syncthreads();
    {   int se = tid >> 3, de = (se + (tid & 7) + 1) & 31;
        float wv = ((se >> 2) == (de >> 2)) ? 0.f : ews[tid];
        nrm[tid] = -dinv[se >> 2] * wv * dinv[de >> 2]; }
    __syncthreads();
    if (tid < 128){
        int v = tid >> 4, ch = (tid & 15)*8;
        float acc[8];
        #pragma unroll
        for (int j = 0; j < 8; ++j) acc[j] = 0.f;
        #pragma unroll
        for (int dd = 0; dd < 4; ++dd){
            int d = v*4 + dd;
            #pragma unroll
            for (int k = 0; k < 8; ++k){
                int sl = (d - k - 1) & 31;
                float nw = nrm[sl*8 + k];
                short8 xv = *(const short8*)&xpb[sl >> 2][ch];
                #pragma unroll
                for (int j = 0; j < 8; ++j) acc[j] = fmaf(nw, bf2f(xv[j]), acc[j]);
            }
        }
        short8 o;
        #pragma unroll
        for (int j = 0; j < 8; ++j) o[j] = f2bf(acc[j]);
        *(short8*)&tx3[((size_t)g*8 + v)*128 + ch] = o;
    }
}

// ---- Flat GEMM: h = xb@Wa + tx@Wb + bias, with per-block channel stats partials
template<int BM, int CIN, int COUT, int NB>
__global__ __launch_bounds__(256) void k_gemm(const short* __restrict__ xb, const short* __restrict__ tx,
        const short* __restrict__ Wa, const short* __restrict__ Wb, int WSP,
        const float* __restrict__ bias, short* __restrict__ h, float* __restrict__ P){
    constexpr int RPW = BM/4, RT = RPW/16, CT = COUT/16, KC = CIN/64;
    __shared__ __align__(16) short As[BM][72];
    __shared__ __align__(16) short Bs[COUT][72];
    __shared__ float ssum[COUT], ssq[COUT];
    int blk = blockIdx.x, tid = threadIdx.x;
    int lane = tid & 63, w = tid >> 6, lrow = lane & 15, lk8 = lane >> 4;
    if (tid < COUT){ ssum[tid] = 0.f; ssq[tid] = 0.f; }
    f32x4 acc[RT][CT];
    #pragma unroll
    for (int rt = 0; rt < RT; ++rt)
        #pragma unroll
        for (int ct = 0; ct < CT; ++ct) acc[rt][ct] = (f32x4){0,0,0,0};

    #pragma unroll
    for (int seg = 0; seg < 2; ++seg){
        const short* Ag = seg ? tx : xb;
        const short* Wg = seg ? Wb : Wa;
        #pragma unroll
        for (int kc = 0; kc < KC; ++kc){
            __syncthreads();
            for (int idx = tid; idx < BM*8; idx += 256){
                int r = idx >> 3, ko = (idx & 7)*8;
                *(short8*)&As[r][ko] =
                    *(const short8*)&Ag[((size_t)(blk*BM + r))*CIN + kc*64 + ko];
            }
            for (int idx = tid; idx < COUT*8; idx += 256){
                int c = idx >> 3, ko = (idx & 7)*8;
                *(short8*)&Bs[c][ko] =
                    *(const short8*)&Wg[(size_t)c*WSP + kc*64 + ko];
            }
            __syncthreads();
            #pragma unroll
            for (int ks = 0; ks < 2; ++ks){
                short8 af[RT];
                #pragma unroll
                for (int rt = 0; rt < RT; ++rt)
                    af[rt] = *(const short8*)&As[w*RPW + rt*16 + lrow][ks*32 + lk8*8];
                #pragma unroll
                for (int ct = 0; ct < CT; ++ct){
                    short8 bf = *(const short8*)&Bs[ct*16 + lrow][ks*32 + lk8*8];
                    #pragma unroll
                    for (int rt = 0; rt < RT; ++rt)
                        acc[rt][ct] = __builtin_amdgcn_mfma_f32_16x16x32_bf16(af[rt], bf, acc[rt][ct], 0, 0, 0);
                }
            }
        }
    }
    // epilogue: bias, store bf16 h, per-channel stats
    #pragma unroll
    for (int ct = 0; ct < CT; ++ct){
        int col = ct*16 + lrow;
        float bb = bias[col];
        float s = 0.f, q = 0.f;
        #pragma unroll
        for (int rt = 0; rt < RT; ++rt){
            #pragma unroll
            for (int e = 0; e < 4; ++e){
                float v = acc[rt][ct][e] + bb;
                int row = blk*BM + w*RPW + rt*16 + lk8*4 + e;
                h[(size_t)row*COUT + col] = f2bf(v);
                s += v; q += v*v;
            }
        }
        s += __shfl_xor(s, 16); s += __shfl_xor(s, 32);
        q += __shfl_xor(q, 16); q += __shfl_xor(q, 32);
        if (lane < 16){ atomicAdd(&ssum[col], s); atomicAdd(&ssq[col], q); }
    }
    __syncthreads();
    if (tid < COUT){
        P[(size_t)tid*NB + blk]          = ssum[tid];
        P[(size_t)(COUT + tid)*NB + blk] = ssq[tid];
    }
}

// ---- finalize stats -> folded scale/shift
template<int C, int NB>
__global__ void k_red(const float* __restrict__ P, const float* __restrict__ gamma,
                      const float* __restrict__ beta, float nl_inv,
                      float* __restrict__ scl, float* __restrict__ sft){
    __shared__ float r1[128], r2[128];
    int c = blockIdx.x, t = threadIdx.x;
    if (t < 128){
        float s = 0.f;
        for (int i = t; i < NB; i += 128) s += P[(size_t)c*NB + i];
        r1[t] = s;
    } else {
        float q = 0.f;
        for (int i = t - 128; i < NB; i += 128) q += P[(size_t)(C + c)*NB + i];
        r2[t - 128] = q;
    }
    __syncthreads();
    for (int s = 64; s > 0; s >>= 1){
        if (t < s) r1[t] += r1[t + s];
        else if (t >= 128 && t - 128 < s) r2[t - 128] += r2[t - 128 + s];
        __syncthreads();
    }
    if (t == 0){
        float m = r1[0] * nl_inv;
        float var = r2[0] * nl_inv - m*m;
        float rs = rsqrtf(var + EPSV) * gamma[c];
        scl[c] = rs;
        sft[c] = beta[c] - m*rs;
    }
}

// ---- head: BN3+sp+mean+FC+log_softmax, one wave per graph
__global__ __launch_bounds__(256) void k_head(const short* __restrict__ h3,
        const float* __restrict__ scl3, const float* __restrict__ sft3,
        const float* __restrict__ fcW, const float* __restrict__ fcb,
        float* __restrict__ out){
    int tid = threadIdx.x, w = tid >> 6, lane = tid & 63;
    int g = blockIdx.x*4 + w;
    int c0 = lane*2;
    float sc0 = scl3[c0], sh0 = sft3[c0];
    float sc1 = scl3[c0+1], sh1 = sft3[c0+1];
    float acc0 = 0.f, acc1 = 0.f;
    #pragma unroll
    for (int n = 0; n < 8; ++n){
        unsigned int v = *(const unsigned int*)&h3[((size_t)g*8 + n)*128 + c0];
        union{unsigned int i; float f;} lo, hi;
        lo.i = v << 16; hi.i = v & 0xffff0000u;
        acc0 += softplus_f(lo.f*sc0 + sh0);
        acc1 += softplus_f(hi.f*sc1 + sh1);
    }
    float hg0 = acc0 * 0.125f, hg1 = acc1 * 0.125f;
    float4 w0 = ((const float4*)fcW)[c0];
    float4 w1 = ((const float4*)fcW)[c0+1];
    float z0 = hg0*w0.x + hg1*w1.x;
    float z1 = hg0*w0.y + hg1*w1.y;
    float z2 = hg0*w0.z + hg1*w1.z;
    float z3 = hg0*w0.w + hg1*w1.w;
    #pragma unroll
    for (int d = 1; d < 64; d <<= 1){
        z0 += __shfl_xor(z0, d); z1 += __shfl_xor(z1, d);
        z2 += __shfl_xor(z2, d); z3 += __shfl_xor(z3, d);
    }
    if (lane == 0){
        z0 += fcb[0]; z1 += fcb[1]; z2 += fcb[2]; z3 += fcb[3];
        float mx = fmaxf(fmaxf(z0, z1), fmaxf(z2, z3));
        float lse = mx + logf(expf(z0-mx) + expf(z1-mx) + expf(z2-mx) + expf(z3-mx));
        *(float4*)(out + (size_t)g*4) = make_float4(z0-lse, z1-lse, z2-lse, z3-lse);
    }
}

extern "C" void kernel_launch(void* const* d_in, const int* in_sizes, int n_in,
                              void* d_out, int out_size, void* d_ws, size_t ws_size,
                              hipStream_t stream){
    const float* x   = (const float*)d_in[0];
    const float* ew  = (const float*)d_in[1];
    const float* W1a = (const float*)d_in[2];
    const float* W1b = (const float*)d_in[3];
    const float* b1  = (const float*)d_in[4];
    const float* g1  = (const float*)d_in[5];
    const float* be1 = (const float*)d_in[6];
    const float* W2a = (const float*)d_in[7];
    const float* W2b = (const float*)d_in[8];
    const float* b2  = (const float*)d_in[9];
    const float* g2  = (const float*)d_in[10];
    const float* be2 = (const float*)d_in[11];
    const float* W3a = (const float*)d_in[12];
    const float* W3b = (const float*)d_in[13];
    const float* b3  = (const float*)d_in[14];
    const float* g3  = (const float*)d_in[15];
    const float* be3 = (const float*)d_in[16];
    const float* fcW = (const float*)d_in[17];
    const float* fcb = (const float*)d_in[18];
    float* out = (float*)d_out;
    (void)in_sizes; (void)n_in; (void)out_size; (void)ws_size;

    short* xb1 = (short*)d_ws;                   // 65536*64
    short* tx1 = xb1 + (size_t)4194304;
    short* h1  = tx1 + (size_t)4194304;
    short* xb2 = h1  + (size_t)4194304;          // 32768*64
    short* tx2 = xb2 + (size_t)2097152;
    short* h2  = tx2 + (size_t)2097152;          // 32768*128
    short* xb3 = h2  + (size_t)4194304;          // 16384*128
    short* tx3 = xb3 + (size_t)2097152;
    short* h3  = tx3 + (size_t)2097152;
    short* wT  = h3  + (size_t)2097152;
    float* fp  = (float*)(((uintptr_t)(wT + WT_TOTAL) + 255) & ~(uintptr_t)255);
    float* P1  = fp;                             // 2*64*512
    float* P2  = P1 + 65536;                     // 2*128*256
    float* P3  = P2 + 65536;                     // 2*128*256
    float* scl1 = P3 + 65536;  float* sft1 = scl1 + 64;
    float* scl2 = sft1 + 64;   float* sft2 = scl2 + 128;
    float* scl3 = sft2 + 128;  float* sft3 = scl3 + 128;

    k_prep<<<224, 256, 0, stream>>>(W1a, W1b, W2a, W2b, W3a, W3b, wT);

    k_gat1<<<2048, 256, 0, stream>>>(x, ew, xb1, tx1);
    k_gemm<128,64,64,512><<<512, 256, 0, stream>>>(xb1, tx1, wT + W1TA_OFF, wT + W1TB_OFF, 72, b1, h1, P1);
    k_red<64,512><<<64, 256, 0, stream>>>(P1, g1, be1, 1.f/65536.f, scl1, sft1);

    k_gat2<<<2048, 256, 0, stream>>>(h1, ew, scl1, sft1, xb2, tx2);
    k_gemm<128,64,128,256><<<256, 256, 0, stream>>>(xb2, tx2, wT + W2TA_OFF, wT + W2TB_OFF, 72, b2, h2, P2);
    k_red<128,256><<<128, 256, 0, stream>>>(P2, g2, be2, 1.f/32768.f, scl2, sft2);

    k_gat3<<<2048, 256, 0, stream>>>(h2, ew, scl2, sft2, xb3, tx3);
    k_gemm<64,128,128,256><<<256, 256, 0, stream>>>(xb3, tx3, wT + W3TA_OFF, wT + W3TB_OFF, 136, b3, h3, P3);
    k_red<128,256><<<128, 256, 0, stream>>>(P3, g3, be3, 1.f/16384.f, scl3, sft3);

    k_head<<<512, 256, 0, stream>>>(h3, scl3, sft3, fcW, fcb, out);
}